// Round 1
// baseline (798.287 us; speedup 1.0000x reference)
//
#include <hip/hip_runtime.h>

#define CIN 16
#define HH 256
#define WW 256
#define HID 128
#define K3C 48          // 3*CIN
#define TH 16
#define TW 16

// Fused: depthwise Sobel (3x3, SAME, zero-pad) -> cat[x,gx,gy] -> 1x1 conv(48->128) -> ReLU -> 1x1 conv(128->16)
__global__ __launch_bounds__(256) void updatenet_fused_f32(
    const float* __restrict__ x,    // [B,16,256,256]
    const float* __restrict__ w1,   // [128,48] (1x1 conv)
    const float* __restrict__ w2,   // [16,128] (1x1 conv)
    float* __restrict__ out)        // [B,16,256,256]
{
    __shared__ float xs[CIN][TH + 2][TW + 2];   // 16*18*18*4 = 20736 B
    __shared__ float w1s[HID * K3C];            // 24576 B
    __shared__ float w2s[CIN * HID];            // 8192 B

    const int b  = blockIdx.z;
    const int i0 = blockIdx.y * TH;
    const int j0 = blockIdx.x * TW;
    const int t  = threadIdx.x;     // 0..255

    // ---- stage weights to LDS (vectorized, coalesced) ----
    {
        const float4* w1v  = (const float4*)w1;   // 1536 float4
        float4*       w1sv = (float4*)w1s;
        #pragma unroll
        for (int r = 0; r < 6; ++r) w1sv[t + 256 * r] = w1v[t + 256 * r];
        const float4* w2v  = (const float4*)w2;   // 512 float4
        float4*       w2sv = (float4*)w2s;
        #pragma unroll
        for (int r = 0; r < 2; ++r) w2sv[t + 256 * r] = w2v[t + 256 * r];
    }

    // ---- stage x tile with halo (zero-pad OOB) ----
    {
        const int total = CIN * 18 * 18;  // 5184
        for (int idx = t; idx < total; idx += 256) {
            const int c  = idx / (18 * 18);
            const int r  = idx % (18 * 18);
            const int ri = r / 18;
            const int rj = r % 18;
            const int ii = i0 + ri - 1;
            const int jj = j0 + rj - 1;
            float v = 0.f;
            if (ii >= 0 && ii < HH && jj >= 0 && jj < WW)
                v = x[((size_t)(b * CIN + c) * HH + ii) * WW + jj];
            xs[c][ri][rj] = v;
        }
    }
    __syncthreads();

    const int ti = t / TW;   // 0..15
    const int tj = t % TW;   // 0..15

    // ---- build cat[48] = [x, grad_x, grad_y] in registers ----
    float cat[K3C];
    #pragma unroll
    for (int c = 0; c < CIN; ++c) {
        const float x00 = xs[c][ti + 0][tj + 0];
        const float x01 = xs[c][ti + 0][tj + 1];
        const float x02 = xs[c][ti + 0][tj + 2];
        const float x10 = xs[c][ti + 1][tj + 0];
        const float x11 = xs[c][ti + 1][tj + 1];
        const float x12 = xs[c][ti + 1][tj + 2];
        const float x20 = xs[c][ti + 2][tj + 0];
        const float x21 = xs[c][ti + 2][tj + 1];
        const float x22 = xs[c][ti + 2][tj + 2];
        cat[c]           = x11;
        // gx = (x02-x00) + 2(x12-x10) + (x22-x20)
        cat[CIN + c]     = (x02 - x00) + 2.f * (x12 - x10) + (x22 - x20);
        // gy = (x20+2x21+x22) - (x00+2x01+x02)
        cat[2 * CIN + c] = (x20 + 2.f * x21 + x22) - (x00 + 2.f * x01 + x02);
    }

    float acc[CIN];
    #pragma unroll
    for (int c = 0; c < CIN; ++c) acc[c] = 0.f;

    // ---- 1x1 convs: h = relu(W1 @ cat); out = W2 @ h ----
    for (int o = 0; o < HID; o += 4) {
        float h[4];
        #pragma unroll
        for (int u = 0; u < 4; ++u) {
            const float4* w1row = (const float4*)&w1s[(o + u) * K3C];
            float s = 0.f;
            #pragma unroll
            for (int k4 = 0; k4 < 12; ++k4) {
                const float4 w = w1row[k4];   // uniform addr -> LDS broadcast
                s += w.x * cat[4 * k4 + 0] + w.y * cat[4 * k4 + 1]
                   + w.z * cat[4 * k4 + 2] + w.w * cat[4 * k4 + 3];
            }
            h[u] = fmaxf(s, 0.f);
        }
        #pragma unroll
        for (int c = 0; c < CIN; ++c) {
            const float4 w = *(const float4*)&w2s[c * HID + o];  // uniform addr
            acc[c] += h[0] * w.x + h[1] * w.y + h[2] * w.z + h[3] * w.w;
        }
    }

    // ---- store [B,16,256,256] ----
    const int oi = i0 + ti;
    const int oj = j0 + tj;
    #pragma unroll
    for (int c = 0; c < CIN; ++c) {
        out[((size_t)(b * CIN + c) * HH + oi) * WW + oj] = acc[c];
    }
}

extern "C" void kernel_launch(void* const* d_in, const int* in_sizes, int n_in,
                              void* d_out, int out_size, void* d_ws, size_t ws_size,
                              hipStream_t stream) {
    const float* x  = (const float*)d_in[0];
    const float* w1 = (const float*)d_in[1];
    const float* w2 = (const float*)d_in[2];
    float* out = (float*)d_out;

    const int Bn = in_sizes[0] / (CIN * HH * WW);   // 32
    dim3 grid(WW / TW, HH / TH, Bn);                // 16 x 16 x 32 = 8192 blocks
    updatenet_fused_f32<<<grid, 256, 0, stream>>>(x, w1, w2, out);
}

// Round 2
// 238.193 us; speedup vs baseline: 3.3514x; 3.3514x over previous
//
#include <hip/hip_runtime.h>

#define CIN 16
#define HH 256
#define WW 256
#define HID 128
#define TH 16
#define TW 16

typedef short short8b __attribute__((ext_vector_type(8)));
typedef float f32x4 __attribute__((ext_vector_type(4)));

// fp32 -> bf16 round-to-nearest-even (finite inputs)
__device__ __forceinline__ unsigned short f2bf(float f) {
    union { float f; unsigned int u; } v; v.f = f;
    unsigned int u = v.u;
    return (unsigned short)((u + 0x7fffu + ((u >> 16) & 1u)) >> 16);
}

// Fused: Sobel (3x3 depthwise) -> cat[x,gx,gy](48) -> bf16 MFMA 1x1 conv(48->128) -> ReLU -> 1x1 conv(128->16)
__global__ __launch_bounds__(256) void updatenet_mfma_bf16(
    const float* __restrict__ x,    // [B,16,256,256]
    const float* __restrict__ w1,   // [128,48]
    const float* __restrict__ w2,   // [16,128]
    float* __restrict__ out)        // [B,16,256,256]
{
    // xs (fp32 halo tile, 20736 B) is reused after sync#2 as per-wave h staging (4 x 4352 B)
    __shared__ alignas(16) float           xs_h[CIN * 18 * 18];       // 20736 B
    __shared__ alignas(16) unsigned short  cat_lds[256 * 72];         // 36864 B  [pixel][K=48 pad 64, stride 72]
    __shared__ alignas(16) unsigned short  w1b[HID * 72];             // 18432 B  [o=128][K=48 pad 64, stride 72]
    __shared__ alignas(16) unsigned short  w2b[CIN * 136];            // 4352 B   [c=16][K=128, stride 136]

    const int b  = blockIdx.z;
    const int i0 = blockIdx.y * TH;
    const int j0 = blockIdx.x * TW;
    const int t  = threadIdx.x;     // 0..255

    // ---- stage W1 -> bf16 LDS [128][72] ----
    {
        const int o = t >> 1, half = t & 1;
        const float* src = w1 + o * 48 + half * 24;
        unsigned short* dst = w1b + o * 72 + half * 24;
        #pragma unroll
        for (int v = 0; v < 3; ++v) {
            short8b s;
            #pragma unroll
            for (int j = 0; j < 8; ++j) s[j] = (short)f2bf(src[8 * v + j]);
            *(short8b*)(dst + 8 * v) = s;
        }
        if (half) {   // zero-pad k = 48..63
            short8b z = (short8b)0;
            *(short8b*)(w1b + o * 72 + 48) = z;
            *(short8b*)(w1b + o * 72 + 56) = z;
        }
    }
    // ---- stage W2 -> bf16 LDS [16][136] ----
    {
        const int c = t >> 4, ch = t & 15;
        const float* src = w2 + c * 128 + ch * 8;
        short8b s;
        #pragma unroll
        for (int j = 0; j < 8; ++j) s[j] = (short)f2bf(src[j]);
        *(short8b*)(w2b + c * 136 + ch * 8) = s;
    }
    // ---- stage x tile + halo (fp32, zero-pad OOB) ----
    {
        const int total = CIN * 18 * 18;  // 5184
        for (int idx = t; idx < total; idx += 256) {
            const int c  = idx / (18 * 18);
            const int r  = idx % (18 * 18);
            const int ri = r / 18;
            const int rj = r % 18;
            const int ii = i0 + ri - 1;
            const int jj = j0 + rj - 1;
            float v = 0.f;
            if (ii >= 0 && ii < HH && jj >= 0 && jj < WW)
                v = x[((size_t)(b * CIN + c) * HH + ii) * WW + jj];
            xs_h[c * 324 + ri * 18 + rj] = v;
        }
    }
    __syncthreads();

    // ---- build cat[48] (fp32 Sobel) and write bf16 to cat_lds[p][*] ----
    {
        const int ti = t >> 4, tj = t & 15;
        float cf[48];
        #pragma unroll
        for (int c = 0; c < CIN; ++c) {
            const float* xc = xs_h + c * 324;
            const float x00 = xc[(ti + 0) * 18 + tj + 0];
            const float x01 = xc[(ti + 0) * 18 + tj + 1];
            const float x02 = xc[(ti + 0) * 18 + tj + 2];
            const float x10 = xc[(ti + 1) * 18 + tj + 0];
            const float x12 = xc[(ti + 1) * 18 + tj + 2];
            const float x20 = xc[(ti + 2) * 18 + tj + 0];
            const float x21 = xc[(ti + 2) * 18 + tj + 1];
            const float x22 = xc[(ti + 2) * 18 + tj + 2];
            const float x11 = xc[(ti + 1) * 18 + tj + 1];
            cf[c]      = x11;
            cf[16 + c] = (x02 - x00) + 2.f * (x12 - x10) + (x22 - x20);
            cf[32 + c] = (x20 + 2.f * x21 + x22) - (x00 + 2.f * x01 + x02);
        }
        unsigned short* catw = cat_lds + t * 72;
        #pragma unroll
        for (int v = 0; v < 6; ++v) {
            short8b s;
            #pragma unroll
            for (int j = 0; j < 8; ++j) s[j] = (short)f2bf(cf[8 * v + j]);
            *(short8b*)(catw + 8 * v) = s;
        }
        short8b z = (short8b)0;
        *(short8b*)(catw + 48) = z;   // zero-pad k = 48..63
        *(short8b*)(catw + 56) = z;
    }
    __syncthreads();   // all xs reads done -> xs region reusable as h staging

    // ---- per-wave GEMM: h = relu(W1 @ cat) ; out = W2 @ h ----
    const int w    = t >> 6;
    const int lane = t & 63;
    const int g    = lane >> 4;     // k-group 0..3
    const int nn   = lane & 15;     // row/col-in-tile

    // A-fragments held in registers for the whole wave
    short8b aW1[8][2];
    #pragma unroll
    for (int m = 0; m < 8; ++m)
        #pragma unroll
        for (int ks = 0; ks < 2; ++ks)
            aW1[m][ks] = *(const short8b*)(w1b + (16 * m + nn) * 72 + 32 * ks + 8 * g);
    short8b aW2[4];
    #pragma unroll
    for (int ks = 0; ks < 4; ++ks)
        aW2[ks] = *(const short8b*)(w2b + nn * 136 + 32 * ks + 8 * g);

    unsigned short* hbuf = ((unsigned short*)xs_h) + w * (16 * 136);  // per-wave [16][136]

    #pragma unroll
    for (int nt = 0; nt < 4; ++nt) {
        const int prow = 64 * w + 16 * nt;

        f32x4 acc[8];
        #pragma unroll
        for (int m = 0; m < 8; ++m) acc[m] = (f32x4)0.f;

        #pragma unroll
        for (int ks = 0; ks < 2; ++ks) {
            const short8b bc = *(const short8b*)(cat_lds + (prow + nn) * 72 + 32 * ks + 8 * g);
            #pragma unroll
            for (int m = 0; m < 8; ++m)
                acc[m] = __builtin_amdgcn_mfma_f32_16x16x32_bf16(aW1[m][ks], bc, acc[m], 0, 0, 0);
        }

        // relu -> bf16 -> per-wave LDS [n=16][k=128]
        #pragma unroll
        for (int m = 0; m < 8; ++m) {
            const unsigned int lo = (unsigned int)f2bf(fmaxf(acc[m][0], 0.f))
                                  | ((unsigned int)f2bf(fmaxf(acc[m][1], 0.f)) << 16);
            const unsigned int hi = (unsigned int)f2bf(fmaxf(acc[m][2], 0.f))
                                  | ((unsigned int)f2bf(fmaxf(acc[m][3], 0.f)) << 16);
            uint2 u; u.x = lo; u.y = hi;
            *(uint2*)(hbuf + nn * 136 + 16 * m + 4 * g) = u;   // k = 16m+4g .. +3, row n = nn
        }
        // same-wave write->read ordering (belt and braces; compiler also inserts lgkmcnt)
        asm volatile("s_waitcnt lgkmcnt(0)" ::: "memory");

        f32x4 acc2 = (f32x4)0.f;
        #pragma unroll
        for (int ks = 0; ks < 4; ++ks) {
            const short8b bh = *(const short8b*)(hbuf + nn * 136 + 32 * ks + 8 * g);
            acc2 = __builtin_amdgcn_mfma_f32_16x16x32_bf16(aW2[ks], bh, acc2, 0, 0, 0);
        }

        // store: lane holds out channels c = 4g+r for pixel p = prow+nn
        const int p   = prow + nn;
        const int oi  = i0 + (p >> 4);
        const int oj  = j0 + (p & 15);
        #pragma unroll
        for (int r = 0; r < 4; ++r) {
            const int c = 4 * g + r;
            out[((size_t)(b * CIN + c) * HH + oi) * WW + oj] = acc2[r];
        }
    }
}

extern "C" void kernel_launch(void* const* d_in, const int* in_sizes, int n_in,
                              void* d_out, int out_size, void* d_ws, size_t ws_size,
                              hipStream_t stream) {
    const float* x  = (const float*)d_in[0];
    const float* w1 = (const float*)d_in[1];
    const float* w2 = (const float*)d_in[2];
    float* out = (float*)d_out;

    const int Bn = in_sizes[0] / (CIN * HH * WW);   // 32
    dim3 grid(WW / TW, HH / TH, Bn);                // 16 x 16 x 32 = 8192 blocks
    updatenet_mfma_bf16<<<grid, 256, 0, stream>>>(x, w1, w2, out);
}

// Round 4
// 217.133 us; speedup vs baseline: 3.6765x; 1.0970x over previous
//
#include <hip/hip_runtime.h>

#define CIN 16
#define HH 256
#define WW 256
#define HID 128
#define TH 32            // tile rows per block
#define TW 16            // tile cols per block
#define KEFF 144         // 9 taps * 16 channels
#define WS_BYTES (HID * KEFF * 2 + CIN * HID * 2)   // 36864 + 4096 = 40960

typedef short short8b __attribute__((ext_vector_type(8)));
typedef float f32x4 __attribute__((ext_vector_type(4)));

// fp32 -> bf16 round-to-nearest-even (finite inputs)
__device__ __forceinline__ unsigned short f2bf(float f) {
    union { float f; unsigned int u; } v; v.f = f;
    unsigned int u = v.u;
    return (unsigned short)((u + 0x7fffu + ((u >> 16) & 1u)) >> 16);
}

// Pre-kernel: Weff[o][tap][c] = W1[o][c]*delta(tap==4) + W1[o][16+c]*Sx[tap] + W1[o][32+c]*Sy[tap]
__global__ __launch_bounds__(256) void build_weff(
    const float* __restrict__ w1, const float* __restrict__ w2,
    unsigned short* __restrict__ ws)
{
    const float SX[9] = {-1.f, 0.f, 1.f, -2.f, 0.f, 2.f, -1.f, 0.f, 1.f};
    const float SY[9] = {-1.f, -2.f, -1.f, 0.f, 0.f, 0.f, 1.f, 2.f, 1.f};
    const int idx = blockIdx.x * 256 + threadIdx.x;
    if (idx < HID * KEFF) {
        const int o = idx / KEFF, r = idx % KEFF;
        const int tap = r >> 4, c = r & 15;
        float v = w1[o * 48 + 16 + c] * SX[tap] + w1[o * 48 + 32 + c] * SY[tap];
        if (tap == 4) v += w1[o * 48 + c];
        ws[idx] = f2bf(v);
    } else if (idx < HID * KEFF + CIN * HID) {
        ws[idx] = f2bf(w2[idx - HID * KEFF]);
    }
}

// smem carve (bytes):
//   weff : [0, 36864)        [128][144] bf16, row stride 288 B
//   guard: [36864, 36880)    zero-initialized (defense; nothing should read it now)
//   w2b  : [36880, 41232)    [16][136] bf16, row stride 272 B
//   xl   : [41232, 60816)    [34][18][16] bf16 channel-last, pixel stride 32 B
//   zreg : [60816, 60848)    32 B zeros (B-source for k>=144)
//   hall : [60848, 78256)    4 waves x [16][136] bf16 h staging
#define SM_WEFF  0
#define SM_GUARD 36864
#define SM_W2B   36880
#define SM_XL    41232
#define SM_ZREG  60816
#define SM_HALL  60848
#define SM_TOTAL 78256

template <bool USE_WS>
__global__ __launch_bounds__(256, 2) void updatenet_im2col(
    const float* __restrict__ x,     // [B,16,256,256]
    const float* __restrict__ w1f,   // [128,48]
    const float* __restrict__ w2f,   // [16,128]
    const unsigned short* __restrict__ ws,  // bf16 weff[128][144] + w2[16][128]
    float* __restrict__ out)         // [B,16,256,256]
{
    __shared__ __align__(16) unsigned char smem[SM_TOTAL];
    unsigned short* weff = (unsigned short*)(smem + SM_WEFF);
    unsigned short* w2b  = (unsigned short*)(smem + SM_W2B);
    unsigned short* xl   = (unsigned short*)(smem + SM_XL);
    unsigned short* zreg = (unsigned short*)(smem + SM_ZREG);

    const int b  = blockIdx.z;
    const int i0 = blockIdx.y * TH;
    const int j0 = blockIdx.x * TW;
    const int t  = threadIdx.x;     // 0..255

    // ---- stage weights ----
    if (USE_WS) {
        const uint4* s1 = (const uint4*)ws;          // 2304 uint4 of weff
        uint4* d1 = (uint4*)weff;
        #pragma unroll
        for (int r = 0; r < 9; ++r) d1[t + 256 * r] = s1[t + 256 * r];
        // w2: [16][128] -> [16][136]; row = 16 uint4
        const uint4* s2 = (const uint4*)(ws + HID * KEFF);
        const int c = t >> 4, q = t & 15;
        ((uint4*)w2b)[c * 17 + q] = s2[c * 16 + q];
    } else {
        for (int idx = t; idx < HID * KEFF; idx += 256) {
            const float SX[9] = {-1.f, 0.f, 1.f, -2.f, 0.f, 2.f, -1.f, 0.f, 1.f};
            const float SY[9] = {-1.f, -2.f, -1.f, 0.f, 0.f, 0.f, 1.f, 2.f, 1.f};
            const int o = idx / KEFF, r = idx % KEFF;
            const int tap = r >> 4, cc = r & 15;
            float v = w1f[o * 48 + 16 + cc] * SX[tap] + w1f[o * 48 + 32 + cc] * SY[tap];
            if (tap == 4) v += w1f[o * 48 + cc];
            weff[idx] = f2bf(v);
        }
        for (int idx = t; idx < CIN * HID; idx += 256) {
            w2b[(idx >> 7) * 136 + (idx & 127)] = f2bf(w2f[idx]);
        }
    }

    // ---- stage x tile (channel-last bf16, zero-pad OOB) ----
    {
        const size_t cs = (size_t)HH * WW;          // channel stride
        for (int p = t; p < 34 * 18; p += 256) {
            const int ri = p / 18, rj = p % 18;
            const int ii = i0 + ri - 1, jj = j0 + rj - 1;
            const bool ok = (ii >= 0) & (ii < HH) & (jj >= 0) & (jj < WW);
            const float* xp = x + ((size_t)b * CIN * HH + ii) * WW + jj;
            short8b s0, s1;
            #pragma unroll
            for (int c = 0; c < 8; ++c) {
                s0[c] = ok ? (short)f2bf(xp[c * cs]) : (short)0;
                s1[c] = ok ? (short)f2bf(xp[(c + 8) * cs]) : (short)0;
            }
            *(short8b*)(xl + p * 16)     = s0;
            *(short8b*)(xl + p * 16 + 8) = s1;
        }
        if (t < 2) *(short8b*)(zreg + t * 8) = (short8b)0;
        if (t == 2) *(short8b*)(smem + SM_GUARD) = (short8b)0;   // never NaN, even if read
    }
    __syncthreads();

    // ---- per-wave GEMM ----
    const int w    = t >> 6;
    const int lane = t & 63;
    const int g    = lane >> 4;     // k-group 0..3
    const int nn   = lane & 15;     // row/col-in-tile
    const int gh   = g >> 1, gl = g & 1;

    // A1 fragments. ks<4: k = 32ks+8g. ks=4: k = 128+8*gl — correct payload for
    // g=0,1 (k=128..143); for g=2,3 it re-reads in-row data that is multiplied by
    // a zero B fragment. NO lane reads outside its own 144-element weff row
    // (round-3 bug: g>=2 overran row 127 into uninitialized LDS -> NaN -> relu
    // cleansed it to 0 -> h[127]=0 -> absmax 0.25).
    short8b aW1[8][5];
    #pragma unroll
    for (int m = 0; m < 8; ++m) {
        #pragma unroll
        for (int ks = 0; ks < 5; ++ks) {
            const int ak = (ks == 4) ? (128 + 8 * gl) : (32 * ks + 8 * g);
            aW1[m][ks] = *(const short8b*)(weff + (16 * m + nn) * KEFF + ak);
        }
    }

    // per-lane tap byte-offsets into xl: tap = 2ks+gh, (di,dj) = (tap/3, tap%3)
    int off[5];
    #pragma unroll
    for (int ks = 0; ks < 5; ++ks) {
        int tap = 2 * ks + gh;
        if (tap > 8) tap = 8;       // ks=4,gh=1 -> redirected to zreg below
        off[ks] = ((tap / 3) * 18 + (tap % 3)) * 32 + gl * 16;
    }

    unsigned short* hb = (unsigned short*)(smem + SM_HALL) + w * (16 * 136);

    for (int nt = 0; nt < 8; ++nt) {
        const int i = 8 * w + nt;                 // output row within tile
        const unsigned char* xbase = (const unsigned char*)xl + (i * 18 + nn) * 32;

        f32x4 acc[8];
        #pragma unroll
        for (int m = 0; m < 8; ++m) acc[m] = (f32x4)0.f;

        #pragma unroll
        for (int ks = 0; ks < 5; ++ks) {
            const unsigned char* bp = (ks == 4 && gh) ? (const unsigned char*)(zreg + gl * 8)
                                                      : xbase + off[ks];
            const short8b bfrag = *(const short8b*)bp;
            #pragma unroll
            for (int m = 0; m < 8; ++m)
                acc[m] = __builtin_amdgcn_mfma_f32_16x16x32_bf16(aW1[m][ks], bfrag, acc[m], 0, 0, 0);
        }

        // relu -> bf16 -> per-wave h staging [pixel nn][o]
        #pragma unroll
        for (int m = 0; m < 8; ++m) {
            const unsigned int lo = (unsigned int)f2bf(fmaxf(acc[m][0], 0.f))
                                  | ((unsigned int)f2bf(fmaxf(acc[m][1], 0.f)) << 16);
            const unsigned int hi = (unsigned int)f2bf(fmaxf(acc[m][2], 0.f))
                                  | ((unsigned int)f2bf(fmaxf(acc[m][3], 0.f)) << 16);
            uint2 u; u.x = lo; u.y = hi;
            *(uint2*)(hb + nn * 136 + 16 * m + 4 * g) = u;
        }
        asm volatile("s_waitcnt lgkmcnt(0)" ::: "memory");

        f32x4 a2 = (f32x4)0.f;
        #pragma unroll
        for (int ks = 0; ks < 4; ++ks) {
            const short8b aw2 = *(const short8b*)(w2b + nn * 136 + 32 * ks + 8 * g);
            const short8b bh  = *(const short8b*)(hb + nn * 136 + 32 * ks + 8 * g);
            a2 = __builtin_amdgcn_mfma_f32_16x16x32_bf16(aw2, bh, a2, 0, 0, 0);
        }

        // store: lane holds out channels c = 4g+r for pixel (i, nn)
        const int oi = i0 + i, oj = j0 + nn;
        float* op = out + ((size_t)(b * CIN + 4 * g) * HH + oi) * WW + oj;
        #pragma unroll
        for (int r = 0; r < 4; ++r)
            op[(size_t)r * HH * WW] = a2[r];
    }
}

extern "C" void kernel_launch(void* const* d_in, const int* in_sizes, int n_in,
                              void* d_out, int out_size, void* d_ws, size_t ws_size,
                              hipStream_t stream) {
    const float* x  = (const float*)d_in[0];
    const float* w1 = (const float*)d_in[1];
    const float* w2 = (const float*)d_in[2];
    float* out = (float*)d_out;

    const int Bn = in_sizes[0] / (CIN * HH * WW);   // 32
    dim3 grid(WW / TW, HH / TH, Bn);                // 16 x 8 x 32 = 4096 blocks

    if (ws_size >= (size_t)WS_BYTES) {
        unsigned short* ws = (unsigned short*)d_ws;
        build_weff<<<(HID * KEFF + CIN * HID + 255) / 256, 256, 0, stream>>>(w1, w2, ws);
        updatenet_im2col<true><<<grid, 256, 0, stream>>>(x, w1, w2, ws, out);
    } else {
        updatenet_im2col<false><<<grid, 256, 0, stream>>>(x, w1, w2, nullptr, out);
    }
}

// Round 5
// 175.848 us; speedup vs baseline: 4.5396x; 1.2348x over previous
//
#include <hip/hip_runtime.h>

#define CIN 16
#define HH 256
#define WW 256
#define HID 128
#define TH 32            // tile rows per block
#define TW 16            // tile cols per block
#define KEFF 144         // 9 taps * 16 channels
#define HSTRIDE 152      // hbuf row stride (elems): 304B = 16B-aligned, bank-balanced
#define WS_BYTES (HID * KEFF * 2 + CIN * HID * 2)   // 36864 + 4096 = 40960

typedef short short8b __attribute__((ext_vector_type(8)));
typedef float f32x4 __attribute__((ext_vector_type(4)));

// fp32 -> bf16 round-to-nearest-even (finite inputs)
__device__ __forceinline__ unsigned short f2bf(float f) {
    union { float f; unsigned int u; } v; v.f = f;
    unsigned int u = v.u;
    return (unsigned short)((u + 0x7fffu + ((u >> 16) & 1u)) >> 16);
}

// Pre-kernel: Weff[o][tap][c] = W1[o][c]*d(tap==4) + W1[o][16+c]*Sx + W1[o][32+c]*Sy ; then w2 bf16.
__global__ __launch_bounds__(256) void build_weff(
    const float* __restrict__ w1, const float* __restrict__ w2,
    unsigned short* __restrict__ ws)
{
    const float SX[9] = {-1.f, 0.f, 1.f, -2.f, 0.f, 2.f, -1.f, 0.f, 1.f};
    const float SY[9] = {-1.f, -2.f, -1.f, 0.f, 0.f, 0.f, 1.f, 2.f, 1.f};
    const int idx = blockIdx.x * 256 + threadIdx.x;
    if (idx < HID * KEFF) {
        const int o = idx / KEFF, r = idx % KEFF;
        const int tap = r >> 4, c = r & 15;
        float v = w1[o * 48 + 16 + c] * SX[tap] + w1[o * 48 + 32 + c] * SY[tap];
        if (tap == 4) v += w1[o * 48 + c];
        ws[idx] = f2bf(v);
    } else if (idx < HID * KEFF + CIN * HID) {
        ws[idx] = f2bf(w2[idx - HID * KEFF]);
    }
}

// LDS carve (bytes):
//   xl   : [0, 19584)         [34][18][16] bf16 channel-last, 32 B/pixel
//   hbuf : [19584, 39040)     [2 pairs][2 phases][16 pix][HSTRIDE] bf16
//   zreg : [39040, 39072)     32 B zeros
#define SM5_XL  0
#define SM5_HB  19584
#define SM5_ZR  39040
#define SM5_TOT 39072

__global__ __launch_bounds__(256, 3) void updatenet_v5(
    const float* __restrict__ x,             // [B,16,256,256]
    const unsigned short* __restrict__ ws,   // bf16 weff[128][144] + w2[16][128]
    float* __restrict__ out)                 // [B,16,256,256]
{
    __shared__ __align__(16) unsigned char smem[SM5_TOT];
    unsigned short* xl   = (unsigned short*)(smem + SM5_XL);
    unsigned short* zreg = (unsigned short*)(smem + SM5_ZR);

    const int b  = blockIdx.z;
    const int i0 = blockIdx.y * TH;
    const int j0 = blockIdx.x * TW;
    const int t  = threadIdx.x;     // 0..255

    // ---- stage x tile (channel-last bf16, zero-pad OOB) ----
    {
        const size_t cs = (size_t)HH * WW;
        for (int pidx = t; pidx < 34 * 18; pidx += 256) {
            const int ri = pidx / 18, rj = pidx % 18;
            const int ii = i0 + ri - 1, jj = j0 + rj - 1;
            const bool ok = (ii >= 0) & (ii < HH) & (jj >= 0) & (jj < WW);
            const float* xp = x + ((size_t)b * CIN * HH + ii) * WW + jj;
            short8b s0, s1;
            #pragma unroll
            for (int c = 0; c < 8; ++c) {
                s0[c] = ok ? (short)f2bf(xp[c * cs]) : (short)0;
                s1[c] = ok ? (short)f2bf(xp[(c + 8) * cs]) : (short)0;
            }
            *(short8b*)(xl + pidx * 16)     = s0;
            *(short8b*)(xl + pidx * 16 + 8) = s1;
        }
        if (t < 2) *(short8b*)(zreg + t * 8) = (short8b)0;
    }

    const int wv   = t >> 6;
    const int lane = t & 63;
    const int p    = wv >> 1;       // pixel half: rows 16p .. 16p+15
    const int q    = wv & 1;        // o half: o in [64q, 64q+64)
    const int g    = lane >> 4;     // k-group 0..3
    const int nn   = lane & 15;     // MFMA row/col-in-tile
    const int gh   = g >> 1, gl = g & 1;

    // ---- A1 fragments RESIDENT: 4 m-tiles x 5 k-chunks, from global ws (L2-hot) ----
    // ks<4: k = 32ks+8g. ks=4: k = 128+8*gl (correct payload for g=0,1; g>=2 re-reads
    // in-row data multiplied by zero B — proven round-4 clamp, never leaves the row).
    short8b aW1[4][5];
    #pragma unroll
    for (int mt = 0; mt < 4; ++mt) {
        #pragma unroll
        for (int ks = 0; ks < 5; ++ks) {
            const int ak = (ks == 4) ? (128 + 8 * gl) : (32 * ks + 8 * g);
            aW1[mt][ks] = *(const short8b*)(ws + (size_t)(64 * q + 16 * mt + nn) * KEFF + ak);
        }
    }
    // A2 fragments resident (w2 bf16 at ws + HID*KEFF, row-major [16][128])
    short8b aW2[4];
    #pragma unroll
    for (int ks = 0; ks < 4; ++ks)
        aW2[ks] = *(const short8b*)(ws + HID * KEFF + nn * HID + 32 * ks + 8 * g);

    // per-lane tap byte-offsets into xl: tap = 2ks+gh, (di,dj) = (tap/3, tap%3)
    int off[5];
    #pragma unroll
    for (int ks = 0; ks < 5; ++ks) {
        int tap = 2 * ks + gh;
        if (tap > 8) tap = 8;       // ks=4,gh=1 -> B redirected to zreg
        off[ks] = ((tap / 3) * 18 + (tap % 3)) * 32 + gl * 16;
    }

    unsigned short* hbp = (unsigned short*)(smem + SM5_HB) + p * (2 * 16 * HSTRIDE);

    __syncthreads();

    // ---- 16 rows per pair; dbuf phases; alternating layer-2 worker ----
    #pragma unroll 2
    for (int s = 0; s < 16; ++s) {
        const int row = 16 * p + s;
        const unsigned char* xbase = (const unsigned char*)xl + (row * 18 + nn) * 32;

        // layer-1: h-half[o 64q..][pix row,0..15]
        f32x4 acc[4];
        #pragma unroll
        for (int mt = 0; mt < 4; ++mt) acc[mt] = (f32x4)0.f;

        #pragma unroll
        for (int ks = 0; ks < 5; ++ks) {
            const unsigned char* bp = (ks == 4 && gh) ? (const unsigned char*)(zreg + gl * 8)
                                                      : xbase + off[ks];
            const short8b bfrag = *(const short8b*)bp;
            #pragma unroll
            for (int mt = 0; mt < 4; ++mt)
                acc[mt] = __builtin_amdgcn_mfma_f32_16x16x32_bf16(aW1[mt][ks], bfrag, acc[mt], 0, 0, 0);
        }

        // relu -> bf16 -> shared hbuf phase s&1; columns 64q+16mt+4g+{0..3}, pixel nn
        unsigned short* hph = hbp + (s & 1) * (16 * HSTRIDE);
        #pragma unroll
        for (int mt = 0; mt < 4; ++mt) {
            const unsigned int lo = (unsigned int)f2bf(fmaxf(acc[mt][0], 0.f))
                                  | ((unsigned int)f2bf(fmaxf(acc[mt][1], 0.f)) << 16);
            const unsigned int hi = (unsigned int)f2bf(fmaxf(acc[mt][2], 0.f))
                                  | ((unsigned int)f2bf(fmaxf(acc[mt][3], 0.f)) << 16);
            uint2 u; u.x = lo; u.y = hi;
            *(uint2*)(hph + nn * HSTRIDE + 64 * q + 16 * mt + 4 * g) = u;
        }

        __syncthreads();   // h(s) visible; also fences phase reuse (s-2 readers done)

        // layer-2 (full K=128) by alternating worker wave; other wave runs ahead into s+1
        if (q == (s & 1)) {
            f32x4 a2 = (f32x4)0.f;
            #pragma unroll
            for (int ks2 = 0; ks2 < 4; ++ks2) {
                const short8b bh = *(const short8b*)(hph + nn * HSTRIDE + 32 * ks2 + 8 * g);
                a2 = __builtin_amdgcn_mfma_f32_16x16x32_bf16(aW2[ks2], bh, a2, 0, 0, 0);
            }
            const int oi = i0 + row, oj = j0 + nn;
            float* op = out + ((size_t)(b * CIN + 4 * g) * HH + oi) * WW + oj;
            #pragma unroll
            for (int r = 0; r < 4; ++r)
                op[(size_t)r * HH * WW] = a2[r];
        }
    }
}

// ---------- fallback (no usable ws): round-4 kernel, weff built in LDS ----------
#define SM_WEFF  0
#define SM_GUARD 36864
#define SM_W2B   36880
#define SM_XL    41232
#define SM_ZREG  60816
#define SM_HALL  60848
#define SM_TOTAL 78256

__global__ __launch_bounds__(256, 2) void updatenet_fallback(
    const float* __restrict__ x, const float* __restrict__ w1f,
    const float* __restrict__ w2f, float* __restrict__ out)
{
    __shared__ __align__(16) unsigned char smem[SM_TOTAL];
    unsigned short* weff = (unsigned short*)(smem + SM_WEFF);
    unsigned short* w2b  = (unsigned short*)(smem + SM_W2B);
    unsigned short* xl   = (unsigned short*)(smem + SM_XL);
    unsigned short* zreg = (unsigned short*)(smem + SM_ZREG);

    const int b  = blockIdx.z;
    const int i0 = blockIdx.y * TH;
    const int j0 = blockIdx.x * TW;
    const int t  = threadIdx.x;

    for (int idx = t; idx < HID * KEFF; idx += 256) {
        const float SX[9] = {-1.f, 0.f, 1.f, -2.f, 0.f, 2.f, -1.f, 0.f, 1.f};
        const float SY[9] = {-1.f, -2.f, -1.f, 0.f, 0.f, 0.f, 1.f, 2.f, 1.f};
        const int o = idx / KEFF, r = idx % KEFF;
        const int tap = r >> 4, cc = r & 15;
        float v = w1f[o * 48 + 16 + cc] * SX[tap] + w1f[o * 48 + 32 + cc] * SY[tap];
        if (tap == 4) v += w1f[o * 48 + cc];
        weff[idx] = f2bf(v);
    }
    for (int idx = t; idx < CIN * HID; idx += 256)
        w2b[(idx >> 7) * 136 + (idx & 127)] = f2bf(w2f[idx]);

    {
        const size_t cs = (size_t)HH * WW;
        for (int pp = t; pp < 34 * 18; pp += 256) {
            const int ri = pp / 18, rj = pp % 18;
            const int ii = i0 + ri - 1, jj = j0 + rj - 1;
            const bool ok = (ii >= 0) & (ii < HH) & (jj >= 0) & (jj < WW);
            const float* xp = x + ((size_t)b * CIN * HH + ii) * WW + jj;
            short8b s0, s1;
            #pragma unroll
            for (int c = 0; c < 8; ++c) {
                s0[c] = ok ? (short)f2bf(xp[c * cs]) : (short)0;
                s1[c] = ok ? (short)f2bf(xp[(c + 8) * cs]) : (short)0;
            }
            *(short8b*)(xl + pp * 16)     = s0;
            *(short8b*)(xl + pp * 16 + 8) = s1;
        }
        if (t < 2) *(short8b*)(zreg + t * 8) = (short8b)0;
        if (t == 2) *(short8b*)(smem + SM_GUARD) = (short8b)0;
    }
    __syncthreads();

    const int w = t >> 6, lane = t & 63;
    const int g = lane >> 4, nn = lane & 15;
    const int gh = g >> 1, gl = g & 1;

    short8b aW1[8][5];
    #pragma unroll
    for (int m = 0; m < 8; ++m)
        #pragma unroll
        for (int ks = 0; ks < 5; ++ks) {
            const int ak = (ks == 4) ? (128 + 8 * gl) : (32 * ks + 8 * g);
            aW1[m][ks] = *(const short8b*)(weff + (16 * m + nn) * KEFF + ak);
        }

    int off[5];
    #pragma unroll
    for (int ks = 0; ks < 5; ++ks) {
        int tap = 2 * ks + gh;
        if (tap > 8) tap = 8;
        off[ks] = ((tap / 3) * 18 + (tap % 3)) * 32 + gl * 16;
    }

    unsigned short* hb = (unsigned short*)(smem + SM_HALL) + w * (16 * 136);

    for (int nt = 0; nt < 8; ++nt) {
        const int i = 8 * w + nt;
        const unsigned char* xbase = (const unsigned char*)xl + (i * 18 + nn) * 32;
        f32x4 acc[8];
        #pragma unroll
        for (int m = 0; m < 8; ++m) acc[m] = (f32x4)0.f;
        #pragma unroll
        for (int ks = 0; ks < 5; ++ks) {
            const unsigned char* bp = (ks == 4 && gh) ? (const unsigned char*)(zreg + gl * 8)
                                                      : xbase + off[ks];
            const short8b bfrag = *(const short8b*)bp;
            #pragma unroll
            for (int m = 0; m < 8; ++m)
                acc[m] = __builtin_amdgcn_mfma_f32_16x16x32_bf16(aW1[m][ks], bfrag, acc[m], 0, 0, 0);
        }
        #pragma unroll
        for (int m = 0; m < 8; ++m) {
            const unsigned int lo = (unsigned int)f2bf(fmaxf(acc[m][0], 0.f))
                                  | ((unsigned int)f2bf(fmaxf(acc[m][1], 0.f)) << 16);
            const unsigned int hi = (unsigned int)f2bf(fmaxf(acc[m][2], 0.f))
                                  | ((unsigned int)f2bf(fmaxf(acc[m][3], 0.f)) << 16);
            uint2 u; u.x = lo; u.y = hi;
            *(uint2*)(hb + nn * 136 + 16 * m + 4 * g) = u;
        }
        asm volatile("s_waitcnt lgkmcnt(0)" ::: "memory");
        f32x4 a2 = (f32x4)0.f;
        #pragma unroll
        for (int ks = 0; ks < 4; ++ks) {
            const short8b aw2 = *(const short8b*)(w2b + nn * 136 + 32 * ks + 8 * g);
            const short8b bh  = *(const short8b*)(hb + nn * 136 + 32 * ks + 8 * g);
            a2 = __builtin_amdgcn_mfma_f32_16x16x32_bf16(aw2, bh, a2, 0, 0, 0);
        }
        const int oi = i0 + i, oj = j0 + nn;
        float* op = out + ((size_t)(b * CIN + 4 * g) * HH + oi) * WW + oj;
        #pragma unroll
        for (int r = 0; r < 4; ++r)
            op[(size_t)r * HH * WW] = a2[r];
    }
}

extern "C" void kernel_launch(void* const* d_in, const int* in_sizes, int n_in,
                              void* d_out, int out_size, void* d_ws, size_t ws_size,
                              hipStream_t stream) {
    const float* x  = (const float*)d_in[0];
    const float* w1 = (const float*)d_in[1];
    const float* w2 = (const float*)d_in[2];
    float* out = (float*)d_out;

    const int Bn = in_sizes[0] / (CIN * HH * WW);   // 32
    dim3 grid(WW / TW, HH / TH, Bn);                // 16 x 8 x 32 = 4096 blocks

    if (ws_size >= (size_t)WS_BYTES) {
        unsigned short* ws = (unsigned short*)d_ws;
        build_weff<<<(HID * KEFF + CIN * HID + 255) / 256, 256, 0, stream>>>(w1, w2, ws);
        updatenet_v5<<<grid, 256, 0, stream>>>(x, ws, out);
    } else {
        updatenet_fallback<<<grid, 256, 0, stream>>>(x, w1, w2, out);
    }
}